// Round 7
// baseline (135.912 us; speedup 1.0000x reference)
//
#include <hip/hip_runtime.h>
#include <math.h>

#define NT 256

// ---- LDS arena offsets (floats). Sizes in comments; verified cumulative. ----
enum : int {
  O_ZERO = 0,      // 32 zeros (shared zero-bias)
  O_NI   = 32,     // 100 (20x5)
  O_VALID= 132,    // 20
  O_SUMM = 152,    // 400 (20x20)
  O_RUN  = 552,    // 20
  O_BACK = 572,    // 400 (20x20)
  O_H1W  = 972,    O_H1B = 1052,   // 80,16
  O_H2W  = 1068,   O_H2B = 1196,   // 128,8
  O_H3W  = 1204,   O_H3B = 1268,   // 64,8
  O_D1W  = 1276,   O_D1B = 1484,   // 208,16
  O_D2W  = 1500,   O_D2B = 1628,   // 128,8
  O_D3W  = 1636,   O_D3B = 1700,   // 64,8
  O_G1W  = 1708,   O_G1B = 1836,   // 128,16
  O_G2W  = 1852,   O_G2B = 1980,   // 128,8
  O_G3W  = 1988,   O_G3B = 2052,   // 64,8
  O_FC1W = 2060,   O_FC1B = 2988,  // 928,32
  O_FC2W = 3020,   O_FC2B = 3532,  // 512,16
  O_FC3W = 3548,   O_FC3B = 3676,  // 128,8
  O_FC4W = 3684,   O_FC4B = 3692,  // 8,1(+pad)
  O_B0   = 3696,   // 640 scratch (max 20x32)
  O_B1   = 4336,   // 320 scratch
  O_GCN  = 4656,   // 160 (20x8)
  O_CC1  = 4816,   // 260 (20x13) concat [ni|gcn]
  O_CC2  = 5076,   // 580 (20x29) concat [ni|gcn|dagx|glob]
  O_DAG  = 5656,   // 160
  O_DAGX = 5816,   // 160
  O_GLOB = 5976,   // 8
  O_LOGIT= 5984,   // 20
  ARENA  = 6004
};

// One layer descriptor: out[r][c] = relu?( b[c] + sum_k in[r*din+k] * w[k<<p | c] )
struct Ld { int rows, din, p, in, w, b, out, relu; };

__constant__ Ld LT[16] = {
  {20,  5, 4, O_NI,   O_H1W,  O_H1B,  O_B0,   1},  // h1
  {20, 16, 3, O_B0,   O_H2W,  O_H2B,  O_B1,   1},  // h2
  {20,  8, 3, O_B1,   O_H3W,  O_H3B,  O_GCN,  1},  // h3 -> gcn
  {20, 13, 4, O_CC1,  O_D1W,  O_D1B,  O_B0,   1},  // d1 (concat input)
  {20, 16, 3, O_B0,   O_D2W,  O_D2B,  O_B1,   1},  // d2
  {20,  8, 3, O_B1,   O_D3W,  O_D3B,  O_B0,   1},  // d3
  {20, 20, 3, O_SUMM, O_B0,   O_ZERO, O_DAG,  0},  // summ @ d3out
  {20,  8, 4, O_DAG,  O_G1W,  O_G1B,  O_B0,   1},  // g1
  {20, 16, 3, O_B0,   O_G2W,  O_G2B,  O_B1,   1},  // g2
  {20,  8, 3, O_B1,   O_G3W,  O_G3B,  O_B0,   1},  // g3
  {20, 20, 3, O_BACK, O_DAG,  O_ZERO, O_DAGX, 0},  // backmap @ dag
  { 1, 20, 3, O_RUN,  O_B0,   O_ZERO, O_GLOB, 0},  // running @ g3out
  {20, 29, 5, O_CC2,  O_FC1W, O_FC1B, O_B0,   1},  // fc1 (concat input)
  {20, 32, 4, O_B0,   O_FC2W, O_FC2B, O_B1,   1},  // fc2
  {20, 16, 3, O_B1,   O_FC3W, O_FC3B, O_B0,   1},  // fc3
  {20,  8, 0, O_B0,   O_FC4W, O_FC4B, O_LOGIT,0},  // fc4 (dout=1)
};

// Single generic dense/matmul engine — exists ONCE in .text (icache-friendly).
__device__ __attribute__((noinline))
void run_layers(float* A, int lo, int hi, int tid) {
  #pragma clang loop unroll(disable)
  for (int L = lo; L < hi; ++L) {
    Ld d = LT[L];
    const int N = d.rows << d.p, msk = (1 << d.p) - 1, st = 1 << d.p;
    #pragma clang loop unroll(disable)
    for (int i = tid; i < N; i += NT) {
      const int r = i >> d.p, c = i & msk;
      float acc = A[d.b + c];
      const float* in = A + d.in + r * d.din;
      const float* wp = A + d.w + c;
      #pragma unroll 4
      for (int k = 0; k < d.din; ++k) { acc = fmaf(in[k], *wp, acc); wp += st; }
      A[d.out + i] = d.relu ? fmaxf(acc, 0.0f) : acc;
    }
    __syncthreads();
  }
}

// Rolled float4 global->LDS copy — one .text copy, many cheap call sites.
__device__ __attribute__((noinline))
void cp4(float* A, int dst, const float* __restrict__ src, int n, int tid) {
  float4* d4 = (float4*)(A + dst);
  const float4* s4 = (const float4*)src;
  #pragma clang loop unroll(disable)
  for (int i = tid; i < (n >> 2); i += NT) d4[i] = s4[i];
}

__global__ __launch_bounds__(NT)
void fused_net_kernel(const float* __restrict__ inp,
                      const float* __restrict__ h1w, const float* __restrict__ h1b,
                      const float* __restrict__ h2w, const float* __restrict__ h2b,
                      const float* __restrict__ h3w, const float* __restrict__ h3b,
                      const float* __restrict__ d1w, const float* __restrict__ d1b,
                      const float* __restrict__ d2w, const float* __restrict__ d2b,
                      const float* __restrict__ d3w, const float* __restrict__ d3b,
                      const float* __restrict__ g1w, const float* __restrict__ g1b,
                      const float* __restrict__ g2w, const float* __restrict__ g2b,
                      const float* __restrict__ g3w, const float* __restrict__ g3b,
                      const float* __restrict__ fc1w, const float* __restrict__ fc1b,
                      const float* __restrict__ fc2w, const float* __restrict__ fc2b,
                      const float* __restrict__ fc3w, const float* __restrict__ fc3b,
                      const float* __restrict__ fc4w, const float* __restrict__ fc4b,
                      float* __restrict__ out) {
  const int tid = threadIdx.x;
  __shared__ __align__(16) float A[ARENA];

  // ---- stage: zero-bias region + all live inputs/weights (float4 bursts) ----
  if (tid < 32) A[O_ZERO + tid] = 0.0f;
  cp4(A, O_NI,    inp,        100, tid);
  cp4(A, O_VALID, inp + 100,  20,  tid);
  cp4(A, O_SUMM,  inp + 3480, 400, tid);
  cp4(A, O_RUN,   inp + 3880, 20,  tid);
  cp4(A, O_BACK,  inp + 3900, 400, tid);
  cp4(A, O_H1W, h1w, 80, tid);   cp4(A, O_H1B, h1b, 16, tid);
  cp4(A, O_H2W, h2w, 128, tid);  cp4(A, O_H2B, h2b, 8, tid);
  cp4(A, O_H3W, h3w, 64, tid);   cp4(A, O_H3B, h3b, 8, tid);
  cp4(A, O_D1W, d1w, 208, tid);  cp4(A, O_D1B, d1b, 16, tid);
  cp4(A, O_D2W, d2w, 128, tid);  cp4(A, O_D2B, d2b, 8, tid);
  cp4(A, O_D3W, d3w, 64, tid);   cp4(A, O_D3B, d3b, 8, tid);
  cp4(A, O_G1W, g1w, 128, tid);  cp4(A, O_G1B, g1b, 16, tid);
  cp4(A, O_G2W, g2w, 128, tid);  cp4(A, O_G2B, g2b, 8, tid);
  cp4(A, O_G3W, g3w, 64, tid);   cp4(A, O_G3B, g3b, 8, tid);
  cp4(A, O_FC1W, fc1w, 928, tid); cp4(A, O_FC1B, fc1b, 32, tid);
  cp4(A, O_FC2W, fc2w, 512, tid); cp4(A, O_FC2B, fc2b, 16, tid);
  cp4(A, O_FC3W, fc3w, 128, tid); cp4(A, O_FC3B, fc3b, 8, tid);
  cp4(A, O_FC4W, fc4w, 8, tid);
  if (tid == 0) A[O_FC4B] = fc4b[0];
  __syncthreads();

  // ---- P0: scatter ni rows into both concat buffers (cols 0:5) ----
  #pragma clang loop unroll(disable)
  for (int i = tid; i < 100; i += NT) {
    int r = i / 5, c = i - r * 5;
    float v = A[O_NI + i];
    A[O_CC1 + r * 13 + c] = v;
    A[O_CC2 + r * 29 + c] = v;
  }
  // (consumed at layer 3; >=3 barriers intervene inside run_layers)

  run_layers(A, 0, 3, tid);   // h1,h2,h3 -> gcn

  // ---- P1: gcn into concat cols 5:13 ----
  #pragma clang loop unroll(disable)
  for (int i = tid; i < 160; i += NT) {
    int r = i >> 3, c = i & 7;
    float v = A[O_GCN + i];
    A[O_CC1 + r * 13 + 5 + c] = v;
    A[O_CC2 + r * 29 + 5 + c] = v;
  }
  __syncthreads();

  run_layers(A, 3, 12, tid);  // d-chain, summ-mm, g-chain, back-mm, glob-mm

  // ---- P2: dag_ext + glob into concat cols 13:21, 21:29 ----
  #pragma clang loop unroll(disable)
  for (int i = tid; i < 160; i += NT) {
    int r = i >> 3, c = i & 7;
    A[O_CC2 + r * 29 + 13 + c] = A[O_DAGX + i];
    A[O_CC2 + r * 29 + 21 + c] = A[O_GLOB + c];
  }
  __syncthreads();

  run_layers(A, 12, 16, tid); // fc1..fc4 -> logits

  // ---- mask + softmax over 20 ----
  if (tid < 20)
    A[O_LOGIT + tid] += (A[O_VALID + tid] - 1.0f) * 10000.0f;
  __syncthreads();
  if (tid < 20) {
    float m = A[O_LOGIT + 0];
    #pragma clang loop unroll(disable)
    for (int r = 1; r < 20; ++r) m = fmaxf(m, A[O_LOGIT + r]);
    float sum = 0.0f;
    #pragma clang loop unroll(disable)
    for (int r = 0; r < 20; ++r) sum += __expf(A[O_LOGIT + r] - m);
    out[tid] = __expf(A[O_LOGIT + tid] - m) / sum;
  }
}

extern "C" void kernel_launch(void* const* d_in, const int* in_sizes, int n_in,
                              void* d_out, int out_size, void* d_ws, size_t ws_size,
                              hipStream_t stream) {
  const float* inp = (const float*)d_in[0];
  // dict order: input, then (w,b) for h1,h2,h3, f1,f2,f3, d1,d2,d3, g1,g2,g3, fc1..fc4
  const float* h1w = (const float*)d_in[1];  const float* h1b = (const float*)d_in[2];
  const float* h2w = (const float*)d_in[3];  const float* h2b = (const float*)d_in[4];
  const float* h3w = (const float*)d_in[5];  const float* h3b = (const float*)d_in[6];
  // f1..f3 (indices 7..12) are dead code: outputs multiplied by zeros(20,1)
  const float* d1w = (const float*)d_in[13]; const float* d1b = (const float*)d_in[14];
  const float* d2w = (const float*)d_in[15]; const float* d2b = (const float*)d_in[16];
  const float* d3w = (const float*)d_in[17]; const float* d3b = (const float*)d_in[18];
  const float* g1w = (const float*)d_in[19]; const float* g1b = (const float*)d_in[20];
  const float* g2w = (const float*)d_in[21]; const float* g2b = (const float*)d_in[22];
  const float* g3w = (const float*)d_in[23]; const float* g3b = (const float*)d_in[24];
  const float* fc1w = (const float*)d_in[25]; const float* fc1b = (const float*)d_in[26];
  const float* fc2w = (const float*)d_in[27]; const float* fc2b = (const float*)d_in[28];
  const float* fc3w = (const float*)d_in[29]; const float* fc3b = (const float*)d_in[30];
  const float* fc4w = (const float*)d_in[31]; const float* fc4b = (const float*)d_in[32];
  float* out = (float*)d_out;

  fused_net_kernel<<<1, NT, 0, stream>>>(inp,
      h1w, h1b, h2w, h2b, h3w, h3b,
      d1w, d1b, d2w, d2b, d3w, d3b,
      g1w, g1b, g2w, g2b, g3w, g3b,
      fc1w, fc1b, fc2w, fc2b, fc3w, fc3b, fc4w, fc4b,
      out);
}